// Round 1
// baseline (1061.856 us; speedup 1.0000x reference)
//
#include <hip/hip_runtime.h>

constexpr int Gn = 5;
constexpr int Bn = 131072;
constexpr int Kn = 512;
constexpr int Dn = 64;
constexpr int TPB = 256;     // threads per block
constexpr int BPT = 2;       // batch elements per thread
constexpr int BTILE = TPB * BPT;   // 512 batch rows per block
constexpr int KCH = 128;     // codebook rows per LDS chunk (32 KB)

constexpr long long QOFF = (long long)Gn * Bn * Dn;  // end of quantized block
constexpr long long IOFF = QOFF + Gn + 1;            // start of indices block

// ---------------------------------------------------------------------------
// e_sq precompute: esq[g*K + k] = sum_d codebooks[g,k,d]^2  (rounding of this
// value is absorbed by the ulp(x_sq)~7.6e-6 grid, any accumulation order ok)
// ---------------------------------------------------------------------------
__global__ void vq_esq(const float* __restrict__ code, float* __restrict__ esq) {
    int i = blockIdx.x * blockDim.x + threadIdx.x;
    if (i >= Gn * Kn) return;
    const float4* c4 = reinterpret_cast<const float4*>(code + (long long)i * Dn);
    float s0 = 0.f, s1 = 0.f, s2 = 0.f, s3 = 0.f;
#pragma unroll
    for (int j = 0; j < 16; ++j) {
        float4 v = c4[j];
        s0 += v.x * v.x; s1 += v.y * v.y; s2 += v.z * v.z; s3 += v.w * v.w;
    }
    esq[i] = (s0 + s1) + (s2 + s3);
}

// ---------------------------------------------------------------------------
// Main kernel: argmin distances + gather quantized + SSE partial per group
// ---------------------------------------------------------------------------
__global__ __launch_bounds__(TPB) void vq_main(
    const float* __restrict__ feat, const float* __restrict__ code,
    const float* __restrict__ esq, float* __restrict__ out,
    float* __restrict__ acc)
{
    __shared__ float sc[KCH * Dn];   // 32 KB codebook chunk
    __shared__ float se[KCH];
    __shared__ float red[TPB / 64];

    const int g = blockIdx.y;
    const int tid = threadIdx.x;
    const long long b0 = (long long)blockIdx.x * BTILE + tid;
    const long long b1 = b0 + TPB;

    const float* fg = feat + (long long)g * Bn * Dn;
    const float* cg = code + (long long)g * Kn * Dn;
    const float* eg = esq + g * Kn;

    // ---- load two feature rows into registers -----------------------------
    float xa[Dn], xb[Dn];
    {
        const float4* p0 = reinterpret_cast<const float4*>(fg + b0 * Dn);
        const float4* p1 = reinterpret_cast<const float4*>(fg + b1 * Dn);
#pragma unroll
        for (int i = 0; i < Dn / 4; ++i) {
            float4 t0 = p0[i]; float4 t1 = p1[i];
            xa[4*i+0] = t0.x; xa[4*i+1] = t0.y; xa[4*i+2] = t0.z; xa[4*i+3] = t0.w;
            xb[4*i+0] = t1.x; xb[4*i+1] = t1.y; xb[4*i+2] = t1.z; xb[4*i+3] = t1.w;
        }
    }

    // ---- x_sq in numpy pairwise-8 order, FMA contraction OFF --------------
    // (bit-exact match with np.sum(features**2, -1) is required: a 1-ulp shift
    //  of x_sq re-randomizes the fp32 tie grid of the distances)
    float xsa, xsb;
    {
#pragma clang fp contract(off)
        float r0[8], r1[8];
#pragma unroll
        for (int j = 0; j < 8; ++j) { r0[j] = xa[j] * xa[j]; r1[j] = xb[j] * xb[j]; }
#pragma unroll
        for (int i = 8; i < Dn; i += 8) {
#pragma unroll
            for (int j = 0; j < 8; ++j) {
                float s0 = xa[i + j] * xa[i + j];
                float s1 = xb[i + j] * xb[i + j];
                r0[j] = r0[j] + s0;
                r1[j] = r1[j] + s1;
            }
        }
        xsa = ((r0[0] + r0[1]) + (r0[2] + r0[3])) + ((r0[4] + r0[5]) + (r0[6] + r0[7]));
        xsb = ((r1[0] + r1[1]) + (r1[2] + r1[3])) + ((r1[4] + r1[5]) + (r1[6] + r1[7]));
    }

    // ---- K loop over LDS-staged codebook chunks ---------------------------
    float bda = 3.4e38f, bdb = 3.4e38f;
    int bka = 0, bkb = 0;

    for (int c = 0; c < Kn / KCH; ++c) {
        {
            const float4* src = reinterpret_cast<const float4*>(cg + (long long)c * KCH * Dn);
            float4* dst = reinterpret_cast<float4*>(sc);
#pragma unroll
            for (int i = 0; i < (KCH * Dn / 4) / TPB; ++i)   // 8 float4 per thread
                dst[tid + i * TPB] = src[tid + i * TPB];
            if (tid < KCH) se[tid] = eg[c * KCH + tid];
        }
        __syncthreads();

        for (int k = 0; k < KCH; ++k) {
            const float4* cr = reinterpret_cast<const float4*>(sc + k * Dn);
            float da0 = 0.f, da1 = 0.f, da2 = 0.f, da3 = 0.f;
            float db0 = 0.f, db1 = 0.f, db2 = 0.f, db3 = 0.f;
#pragma unroll
            for (int i = 0; i < 16; ++i) {
                float4 v = cr[i];   // wave-uniform address -> LDS broadcast
                da0 = fmaf(v.x, xa[4*i+0], da0);
                da1 = fmaf(v.y, xa[4*i+1], da1);
                da2 = fmaf(v.z, xa[4*i+2], da2);
                da3 = fmaf(v.w, xa[4*i+3], da3);
                db0 = fmaf(v.x, xb[4*i+0], db0);
                db1 = fmaf(v.y, xb[4*i+1], db1);
                db2 = fmaf(v.z, xb[4*i+2], db2);
                db3 = fmaf(v.w, xb[4*i+3], db3);
            }
            float dota = (da0 + da1) + (da2 + da3);
            float dotb = (db0 + db1) + (db2 + db3);
            float sek = se[k];
            // mirrors: distances = (x_sq + e_sq) - 2*cross (fma(-2,dot,s) is
            // bit-identical to s - fl(2*dot) since *2 is exact)
            float dista = (xsa + sek) - 2.0f * dota;
            float distb = (xsb + sek) - 2.0f * dotb;
            int kk = c * KCH + k;
            if (dista < bda) { bda = dista; bka = kk; }   // strict <: first-index tie-break
            if (distb < bdb) { bdb = distb; bkb = kk; }
        }
        __syncthreads();
    }

    // ---- epilogue: gather quantized rows, write indices, SSE --------------
    float sse = 0.f;
    {
        const float4* q = reinterpret_cast<const float4*>(cg + (long long)bka * Dn);
        float4* o = reinterpret_cast<float4*>(out + ((long long)g * Bn + b0) * Dn);
#pragma unroll
        for (int i = 0; i < 16; ++i) {
            float4 v = q[i];
            float e0 = v.x - xa[4*i+0], e1 = v.y - xa[4*i+1];
            float e2 = v.z - xa[4*i+2], e3 = v.w - xa[4*i+3];
            sse += e0*e0 + e1*e1 + e2*e2 + e3*e3;
            o[i] = v;
        }
    }
    {
        const float4* q = reinterpret_cast<const float4*>(cg + (long long)bkb * Dn);
        float4* o = reinterpret_cast<float4*>(out + ((long long)g * Bn + b1) * Dn);
#pragma unroll
        for (int i = 0; i < 16; ++i) {
            float4 v = q[i];
            float e0 = v.x - xb[4*i+0], e1 = v.y - xb[4*i+1];
            float e2 = v.z - xb[4*i+2], e3 = v.w - xb[4*i+3];
            sse += e0*e0 + e1*e1 + e2*e2 + e3*e3;
            o[i] = v;
        }
    }
    out[IOFF + (long long)g * Bn + b0] = (float)bka;
    out[IOFF + (long long)g * Bn + b1] = (float)bkb;

    // ---- block reduction of SSE, one atomic per block ---------------------
#pragma unroll
    for (int off = 32; off > 0; off >>= 1) sse += __shfl_down(sse, off);
    if ((tid & 63) == 0) red[tid >> 6] = sse;
    __syncthreads();
    if (tid == 0) {
        float s = (red[0] + red[1]) + (red[2] + red[3]);
        atomicAdd(&acc[g], s);
    }
}

// ---------------------------------------------------------------------------
// Finalize: per_group_loss = 1.25 * SSE / (B*D);  total = sequential sum
// (B*D = 2^23, division exact scaling; tolerance here is huge anyway)
// ---------------------------------------------------------------------------
__global__ void vq_finalize(const float* __restrict__ acc, float* __restrict__ out) {
    if (threadIdx.x == 0 && blockIdx.x == 0) {
        float tot = 0.f;
#pragma unroll
        for (int g = 0; g < Gn; ++g) {
            float m = acc[g] / 8388608.0f;   // mean over B*D = 2^23
            float l = m + 0.25f * m;         // q_latent + 0.25*e_latent
            out[QOFF + g] = l;
            tot += l;                        // sequential: numpy order for n=5
        }
        out[QOFF + Gn] = tot;
    }
}

extern "C" void kernel_launch(void* const* d_in, const int* in_sizes, int n_in,
                              void* d_out, int out_size, void* d_ws, size_t ws_size,
                              hipStream_t stream) {
    const float* feat = (const float*)d_in[0];   // [G,B,D] fp32
    const float* code = (const float*)d_in[1];   // [G,K,D] fp32
    float* out = (float*)d_out;
    float* acc = (float*)d_ws;                   // [G] SSE accumulators
    float* esq = (float*)d_ws + 8;               // [G*K] codebook norms

    hipMemsetAsync(acc, 0, Gn * sizeof(float), stream);
    vq_esq<<<(Gn * Kn + TPB - 1) / TPB, TPB, 0, stream>>>(code, esq);
    dim3 grid(Bn / BTILE, Gn);
    vq_main<<<grid, TPB, 0, stream>>>(feat, code, esq, out, acc);
    vq_finalize<<<1, 64, 0, stream>>>(acc, out);
}